// Round 2
// baseline (86.305 us; speedup 1.0000x reference)
//
#include <hip/hip_runtime.h>
#include <hip/hip_bf16.h>

// KAN layer, fully fused single kernel.
// out(512x256) = (1/128) * F(512x1024) * W^T(256x1024)  [bf16 MFMA, f32 acc]
// Virtual K'=1024: k <-> (i = k>>3, t = k&7); t=0..5 basis, t=6 swish/c_res, t=7 zero pad.
// With 16x16x32 MFMA, lane (r, q=lane>>4) at k-step c holds exactly element i=4c+q,
// t=0..7 -> each lane builds its own A and B fragments in registers. No LDS, no ws.

typedef short short8 __attribute__((ext_vector_type(8)));
typedef float f32x4 __attribute__((ext_vector_type(4)));

static __device__ inline unsigned short bf16_bits(float f) {
    union { __hip_bfloat16 h; unsigned short u; } cvt;
    cvt.h = __float2bfloat16(f);
    return cvt.u;
}

__global__ __launch_bounds__(64) void kan_fused(
    const float* __restrict__ x,        // (512,128)
    const float* __restrict__ grid,     // (32768,10) rows identical, uniform knots
    const float* __restrict__ c_basis,  // (32768,6)
    const float* __restrict__ c_spl,    // (32768,)
    const float* __restrict__ c_res,    // (32768,)
    float* __restrict__ out)            // (512,256)
{
    const int bt   = blockIdx.x >> 4;   // 0..31 batch tile
    const int ot   = blockIdx.x & 15;   // 0..15 output tile
    const int lane = threadIdx.x;
    const int r    = lane & 15;
    const int q    = lane >> 4;

    const int b = bt * 16 + r;          // batch row feeding this lane's A-frag
    const int o = ot * 16 + r;          // output row feeding this lane's B-frag

    // Uniform knot vector: t[s] = t0 + s*h  (h = (hi-lo)/G by construction)
    const float t0    = grid[0];
    const float h     = grid[4] - grid[3];
    const float inv_h = 1.0f / h;       // once per thread, precise

    const float* xrow = x + b * 128;
    const int    jb   = o * 128;

    f32x4 acc = {0.0f, 0.0f, 0.0f, 0.0f};

#pragma unroll 4
    for (int c = 0; c < 32; ++c) {
        const int i = 4 * c + q;

        // ---------- A fragment: cubic B-spline basis + swish of x[b][i] ----------
        const float xv = xrow[i];
        const float u  = (xv - t0) * inv_h;   // knot units

        float d[10];
#pragma unroll
        for (int s = 0; s < 10; ++s) d[s] = u - (float)s;

        float I0[9];   // order-0 indicator: u in [s, s+1)
#pragma unroll
        for (int s = 0; s < 9; ++s)
            I0[s] = (d[s] >= 0.0f && d[s + 1] < 0.0f) ? 1.0f : 0.0f;

        float b1[8];   // order-1 (denominators h folded out)
#pragma unroll
        for (int s = 0; s < 8; ++s)
            b1[s] = d[s] * I0[s] - d[s + 2] * I0[s + 1];

        float b2[7];   // order-2, unscaled (0.5 deferred)
#pragma unroll
        for (int s = 0; s < 7; ++s)
            b2[s] = d[s] * b1[s] - d[s + 3] * b1[s + 1];

        float b3[6];   // order-3, combined scale 1/(2*3) applied once
#pragma unroll
        for (int s = 0; s < 6; ++s)
            b3[s] = (d[s] * b2[s] - d[s + 4] * b2[s + 1]) * (1.0f / 6.0f);

        const float e  = __expf(-xv);
        const float sw = xv * __builtin_amdgcn_rcpf(1.0f + e);   // swish

        short8 af;
        af[0] = bf16_bits(b3[0]);
        af[1] = bf16_bits(b3[1]);
        af[2] = bf16_bits(b3[2]);
        af[3] = bf16_bits(b3[3]);
        af[4] = bf16_bits(b3[4]);
        af[5] = bf16_bits(b3[5]);
        af[6] = bf16_bits(sw);
        af[7] = 0;

        // ---------- B fragment: scaled spline coeffs + residual coeff ----------
        const int    j   = jb + i;
        const float* cbp = c_basis + j * 6;
        const float  spl = c_spl[j];

        short8 bfr;
        bfr[0] = bf16_bits(spl * cbp[0]);
        bfr[1] = bf16_bits(spl * cbp[1]);
        bfr[2] = bf16_bits(spl * cbp[2]);
        bfr[3] = bf16_bits(spl * cbp[3]);
        bfr[4] = bf16_bits(spl * cbp[4]);
        bfr[5] = bf16_bits(spl * cbp[5]);
        bfr[6] = bf16_bits(c_res[j]);
        bfr[7] = 0;

        acc = __builtin_amdgcn_mfma_f32_16x16x32_bf16(af, bfr, acc, 0, 0, 0);
    }

    // C/D layout (m89-verified): col = lane&15 (o), row = (lane>>4)*4 + reg (b)
    const float scale = 1.0f / 128.0f;
    const int   orow  = bt * 16 + q * 4;
    const int   ocol  = ot * 16 + r;
#pragma unroll
    for (int reg = 0; reg < 4; ++reg)
        out[(orow + reg) * 256 + ocol] = acc[reg] * scale;
}

extern "C" void kernel_launch(void* const* d_in, const int* in_sizes, int n_in,
                              void* d_out, int out_size, void* d_ws, size_t ws_size,
                              hipStream_t stream) {
    const float* x       = (const float*)d_in[0];
    const float* grid    = (const float*)d_in[1];
    const float* c_basis = (const float*)d_in[2];
    const float* c_spl   = (const float*)d_in[3];
    const float* c_res   = (const float*)d_in[4];
    float* out = (float*)d_out;

    // 512 tiles of 16x16, one wave each; fully fused, no workspace, no barriers.
    kan_fused<<<512, 64, 0, stream>>>(x, grid, c_basis, c_spl, c_res, out);
}

// Round 3
// 67.649 us; speedup vs baseline: 1.2758x; 1.2758x over previous
//
#include <hip/hip_runtime.h>
#include <hip/hip_bf16.h>

// KAN layer, two-phase, padded feature dim.
// Phase 1 (build_fw): F(512x1024 bf16), W(256x1024 bf16) with k = i*8 + t,
//   t=0..5 cubic B-spline basis / scaled coeffs, t=6 swish / c_res, t=7 zero pad.
//   One thread per (b,i) or per j=(o,i); one aligned 16-B store each.
// Phase 2 (kan_gemm): out(512x256 f32) = (1/128) * F * W^T via mfma_f32_16x16x32_bf16,
//   one wave per 16x16 tile, 32 MFMAs, all operands register-resident.

typedef short short8 __attribute__((ext_vector_type(8)));
typedef float f32x4 __attribute__((ext_vector_type(4)));

static __device__ inline unsigned short bf16_bits(float f) {
    union { __hip_bfloat16 h; unsigned short u; } cvt;
    cvt.h = __float2bfloat16(f);
    return cvt.u;
}

// ---------------------------------------------------------------------------
// Kernel 1: build features F and weights W (padded to 8 per input channel)
// tid <  65536          : one (b,i) -> 6 basis + swish + 0        -> F[tid*8..]
// tid in [65536, 98304) : one j=(o,i) -> 6 scaled coeffs + c_res  -> W[j*8..]
// Block 0..255 are F-only, 256..383 W-only: no intra-block divergence.
// ---------------------------------------------------------------------------
__global__ __launch_bounds__(256) void build_fw(
    const float* __restrict__ x,        // (512,128)
    const float* __restrict__ grid,     // (32768,10) rows identical, uniform
    const float* __restrict__ c_basis,  // (32768,6)
    const float* __restrict__ c_spl,    // (32768,)
    const float* __restrict__ c_res,    // (32768,)
    unsigned short* __restrict__ F,     // (512,1024) bf16 bits
    unsigned short* __restrict__ W)     // (256,1024) bf16 bits
{
    const int tid = blockIdx.x * 256 + threadIdx.x;

    if (tid < 512 * 128) {
        // Uniform knots: t[s] = t0 + s*h. Divide-free Cox-de Boor in knot
        // units u = (x - t0)/h; denominators fold to a single 1/6 scale.
        const float t0    = grid[0];
        const float inv_h = 1.0f / (grid[1] - grid[0]);

        const float xv = x[tid];             // tid = b*128 + i
        const float u  = (xv - t0) * inv_h;

        float d[10];
#pragma unroll
        for (int s = 0; s < 10; ++s) d[s] = u - (float)s;

        float I0[9];
#pragma unroll
        for (int s = 0; s < 9; ++s)
            I0[s] = (d[s] >= 0.0f && d[s + 1] < 0.0f) ? 1.0f : 0.0f;

        float b1[8];
#pragma unroll
        for (int s = 0; s < 8; ++s)
            b1[s] = d[s] * I0[s] - d[s + 2] * I0[s + 1];

        float b2[7];
#pragma unroll
        for (int s = 0; s < 7; ++s)
            b2[s] = d[s] * b1[s] - d[s + 3] * b1[s + 1];

        float b3[6];
#pragma unroll
        for (int s = 0; s < 6; ++s)
            b3[s] = (d[s] * b2[s] - d[s + 4] * b2[s + 1]) * (1.0f / 6.0f);

        const float e  = __expf(-xv);
        const float sw = xv * __builtin_amdgcn_rcpf(1.0f + e);

        short8 v;
        v[0] = bf16_bits(b3[0]);
        v[1] = bf16_bits(b3[1]);
        v[2] = bf16_bits(b3[2]);
        v[3] = bf16_bits(b3[3]);
        v[4] = bf16_bits(b3[4]);
        v[5] = bf16_bits(b3[5]);
        v[6] = bf16_bits(sw);
        v[7] = 0;
        *(short8*)(F + tid * 8) = v;        // one global_store_dwordx4
    } else if (tid < 512 * 128 + 32768) {
        const int j = tid - 512 * 128;      // j = o*128 + i
        const float spl = c_spl[j];
        const float* cbp = c_basis + j * 6;

        short8 v;
        v[0] = bf16_bits(spl * cbp[0]);
        v[1] = bf16_bits(spl * cbp[1]);
        v[2] = bf16_bits(spl * cbp[2]);
        v[3] = bf16_bits(spl * cbp[3]);
        v[4] = bf16_bits(spl * cbp[4]);
        v[5] = bf16_bits(spl * cbp[5]);
        v[6] = bf16_bits(c_res[j]);
        v[7] = 0;
        *(short8*)(W + j * 8) = v;          // one global_store_dwordx4
    }
}

// ---------------------------------------------------------------------------
// Kernel 2: out(512x256 f32) = (1/128) * F * W^T, mfma_f32_16x16x32_bf16.
// One wave per 16x16 tile; K=1024 -> 32 MFMAs. Frag: lane(r,q) holds
// row r, k = 32*c + q*8 + j  (16-B aligned since stride is now 8).
// C/D layout (m89-verified): col = lane&15, row = (lane>>4)*4 + reg.
// ---------------------------------------------------------------------------
__global__ __launch_bounds__(64) void kan_gemm(
    const unsigned short* __restrict__ F,   // (512,1024) bf16
    const unsigned short* __restrict__ W,   // (256,1024) bf16
    float* __restrict__ out)                // (512,256) f32
{
    const int bt   = blockIdx.x >> 4;   // 0..31 batch tile
    const int ot   = blockIdx.x & 15;   // 0..15 output tile
    const int lane = threadIdx.x;
    const int r    = lane & 15;
    const int q    = lane >> 4;

    const unsigned short* fp = F + (bt * 16 + r) * 1024 + q * 8;
    const unsigned short* wp = W + (ot * 16 + r) * 1024 + q * 8;

    f32x4 acc = {0.0f, 0.0f, 0.0f, 0.0f};

#pragma unroll
    for (int k0 = 0; k0 < 1024; k0 += 128) {
        short8 a0 = *(const short8*)(fp + k0);
        short8 a1 = *(const short8*)(fp + k0 + 32);
        short8 a2 = *(const short8*)(fp + k0 + 64);
        short8 a3 = *(const short8*)(fp + k0 + 96);
        short8 w0 = *(const short8*)(wp + k0);
        short8 w1 = *(const short8*)(wp + k0 + 32);
        short8 w2 = *(const short8*)(wp + k0 + 64);
        short8 w3 = *(const short8*)(wp + k0 + 96);
        acc = __builtin_amdgcn_mfma_f32_16x16x32_bf16(a0, w0, acc, 0, 0, 0);
        acc = __builtin_amdgcn_mfma_f32_16x16x32_bf16(a1, w1, acc, 0, 0, 0);
        acc = __builtin_amdgcn_mfma_f32_16x16x32_bf16(a2, w2, acc, 0, 0, 0);
        acc = __builtin_amdgcn_mfma_f32_16x16x32_bf16(a3, w3, acc, 0, 0, 0);
    }

    const float scale = 1.0f / 128.0f;
    const int   orow  = bt * 16 + q * 4;
    const int   ocol  = ot * 16 + r;
#pragma unroll
    for (int reg = 0; reg < 4; ++reg)
        out[(orow + reg) * 256 + ocol] = acc[reg] * scale;
}

extern "C" void kernel_launch(void* const* d_in, const int* in_sizes, int n_in,
                              void* d_out, int out_size, void* d_ws, size_t ws_size,
                              hipStream_t stream) {
    const float* x       = (const float*)d_in[0];
    const float* grid    = (const float*)d_in[1];
    const float* c_basis = (const float*)d_in[2];
    const float* c_spl   = (const float*)d_in[3];
    const float* c_res   = (const float*)d_in[4];
    float* out = (float*)d_out;

    unsigned short* F = (unsigned short*)d_ws;                            // 512*1024*2 B = 1 MiB
    unsigned short* W = (unsigned short*)((char*)d_ws + 512 * 1024 * 2);  // 256*1024*2 B = 512 KiB

    // 65536 feature threads + 32768 weight threads = 98304 = 384 * 256
    build_fw<<<384, 256, 0, stream>>>(x, grid, c_basis, c_spl, c_res, F, W);
    // 512 tiles of 16x16, one wave each
    kan_gemm<<<512, 64, 0, stream>>>(F, W, out);
}

// Round 4
// 66.548 us; speedup vs baseline: 1.2969x; 1.0166x over previous
//
#include <hip/hip_runtime.h>
#include <hip/hip_bf16.h>

// KAN layer, single fused kernel, no workspace.
// out(512x256) = (1/128) * F(512x1024) * W^T(256x1024), bf16 MFMA, f32 acc.
// Virtual K'=1024: k = i*8 + t; t=0..5 cubic B-spline basis / scaled coeffs,
// t=6 swish / c_res, t=7 zero pad.
//
// Grid: 512 blocks = (bt 0..31, ot 0..15), 256 threads (4 waves).
// Per block: build F-tile (16x1024 bf16) and W-tile (16x1024 bf16) in LDS
// cooperatively (coalesced), then one 16x16 MFMA tile with K split across
// the 4 waves; partial accumulators reduced through LDS.
// LDS rows are 2048 B -> XOR-swizzle byte^=(row&7)<<4 so the 16-lane
// fragment reads are 2-way (free) instead of 16-way bank conflicts.

typedef short short8 __attribute__((ext_vector_type(8)));
typedef float f32x4 __attribute__((ext_vector_type(4)));

static __device__ inline unsigned short bf16_bits(float f) {
    union { __hip_bfloat16 h; unsigned short u; } cvt;
    cvt.h = __float2bfloat16(f);
    return cvt.u;
}

__global__ __launch_bounds__(256) void kan_fused(
    const float* __restrict__ x,        // (512,128)
    const float* __restrict__ grid,     // (32768,10) rows identical, uniform
    const float* __restrict__ c_basis,  // (32768,6)
    const float* __restrict__ c_spl,    // (32768,)
    const float* __restrict__ c_res,    // (32768,)
    float* __restrict__ out)            // (512,256)
{
    __shared__ short8 lds_v[4096];              // 64 KiB: F @0, W @32768
    unsigned char* lds = (unsigned char*)lds_v;

    const int bt = blockIdx.x >> 4;             // batch tile 0..31
    const int ot = blockIdx.x & 15;             // output tile 0..15
    const int t  = threadIdx.x;

    // Uniform knots: t[s] = t0 + s*h; divide-free Cox-de Boor in knot units.
    const float t0    = grid[0];
    const float inv_h = 1.0f / (grid[1] - grid[0]);

    // ---------------- build F tile: rows = batch rows bt*16..+16 ----------------
    for (int s = 0; s < 8; ++s) {
        const int e  = s * 256 + t;             // 0..2047
        const int bl = e >> 7;                  // local batch row 0..15
        const int i  = e & 127;                 // input channel

        const float xv = x[(bt * 16 + bl) * 128 + i];
        const float u  = (xv - t0) * inv_h;

        float d[10];
#pragma unroll
        for (int m = 0; m < 10; ++m) d[m] = u - (float)m;

        float I0[9];
#pragma unroll
        for (int m = 0; m < 9; ++m)
            I0[m] = (d[m] >= 0.0f && d[m + 1] < 0.0f) ? 1.0f : 0.0f;

        float b1[8];
#pragma unroll
        for (int m = 0; m < 8; ++m)
            b1[m] = d[m] * I0[m] - d[m + 2] * I0[m + 1];

        float b2[7];
#pragma unroll
        for (int m = 0; m < 7; ++m)
            b2[m] = d[m] * b1[m] - d[m + 3] * b1[m + 1];

        float b3[6];
#pragma unroll
        for (int m = 0; m < 6; ++m)
            b3[m] = (d[m] * b2[m] - d[m + 4] * b2[m + 1]) * (1.0f / 6.0f);

        const float e_  = __expf(-xv);
        const float sw  = xv * __builtin_amdgcn_rcpf(1.0f + e_);

        short8 v;
        v[0] = bf16_bits(b3[0]);
        v[1] = bf16_bits(b3[1]);
        v[2] = bf16_bits(b3[2]);
        v[3] = bf16_bits(b3[3]);
        v[4] = bf16_bits(b3[4]);
        v[5] = bf16_bits(b3[5]);
        v[6] = bf16_bits(sw);
        v[7] = 0;
        *(short8*)(lds + bl * 2048 + ((i * 16) ^ ((bl & 7) << 4))) = v;
    }

    // ---------------- build W tile: rows = output rows ot*16..+16 ----------------
    for (int s = 0; s < 8; ++s) {
        const int e  = s * 256 + t;             // 0..2047
        const int ol = e >> 7;                  // local output row 0..15
        const int i  = e & 127;
        const int j  = (ot * 16 + ol) * 128 + i;

        const float  spl = c_spl[j];
        const float* cbp = c_basis + j * 6;

        short8 v;
        v[0] = bf16_bits(spl * cbp[0]);
        v[1] = bf16_bits(spl * cbp[1]);
        v[2] = bf16_bits(spl * cbp[2]);
        v[3] = bf16_bits(spl * cbp[3]);
        v[4] = bf16_bits(spl * cbp[4]);
        v[5] = bf16_bits(spl * cbp[5]);
        v[6] = bf16_bits(c_res[j]);
        v[7] = 0;
        *(short8*)(lds + 32768 + ol * 2048 + ((i * 16) ^ ((ol & 7) << 4))) = v;
    }

    __syncthreads();

    // ---------------- GEMM: one 16x16 tile, K=1024 split over 4 waves ----------------
    const int wv   = t >> 6;                    // wave 0..3 -> k quarter
    const int lane = t & 63;
    const int r    = lane & 15;
    const int q    = lane >> 4;
    const int xr   = (r & 7) << 4;              // read-side swizzle

    const unsigned char* Fb = lds + r * 2048;
    const unsigned char* Wb = lds + 32768 + r * 2048;

    f32x4 acc = {0.0f, 0.0f, 0.0f, 0.0f};
#pragma unroll
    for (int cc = 0; cc < 8; ++cc) {
        const int c   = wv * 8 + cc;            // k-step 0..31
        const int off = (c * 64 + q * 16) ^ xr;
        short8 a = *(const short8*)(Fb + off);
        short8 b = *(const short8*)(Wb + off);
        acc = __builtin_amdgcn_mfma_f32_16x16x32_bf16(a, b, acc, 0, 0, 0);
    }

    __syncthreads();                            // all F/W reads done
    *(f32x4*)(lds + t * 16) = acc;              // partials alias F region (4 KiB)
    __syncthreads();

    if (t < 64) {
        f32x4 s0 = *(const f32x4*)(lds + t * 16);
        f32x4 s1 = *(const f32x4*)(lds + (64 + t) * 16);
        f32x4 s2 = *(const f32x4*)(lds + (128 + t) * 16);
        f32x4 s3 = *(const f32x4*)(lds + (192 + t) * 16);
        f32x4 sum = (s0 + s1) + (s2 + s3);

        // C/D layout (m89-verified): col = lane&15 (o), row = (lane>>4)*4 + reg (b)
        const float scale = 1.0f / 128.0f;
        const int   orow  = bt * 16 + (t >> 4) * 4;
        const int   ocol  = ot * 16 + (t & 15);
#pragma unroll
        for (int reg = 0; reg < 4; ++reg)
            out[(orow + reg) * 256 + ocol] = sum[reg] * scale;
    }
}

extern "C" void kernel_launch(void* const* d_in, const int* in_sizes, int n_in,
                              void* d_out, int out_size, void* d_ws, size_t ws_size,
                              hipStream_t stream) {
    const float* x       = (const float*)d_in[0];
    const float* grid    = (const float*)d_in[1];
    const float* c_basis = (const float*)d_in[2];
    const float* c_spl   = (const float*)d_in[3];
    const float* c_res   = (const float*)d_in[4];
    float* out = (float*)d_out;

    // Single launch, no workspace, no inter-kernel drain.
    kan_fused<<<512, 256, 0, stream>>>(x, grid, c_basis, c_spl, c_res, out);
}